// Round 16
// baseline (159.155 us; speedup 1.0000x reference)
//
#include <hip/hip_runtime.h>
#include <stdint.h>

#define B_DIM 4096
#define C_DIM 32
#define D_DIM 128
#define R_DIM 8
#define BM    64           // 4 waves x 16 rows
#define NTHREADS 256

typedef __bf16 bf16x8 __attribute__((ext_vector_type(8)));
typedef float  f32x4  __attribute__((ext_vector_type(4)));

// f32 -> bf16 bits, round-to-nearest-even
__device__ __forceinline__ uint32_t f2bf(float f) {
  uint32_t u = __float_as_uint(f);
  return (u + 0x7FFFu + ((u >> 16) & 1u)) >> 16;
}

#if __has_builtin(__builtin_amdgcn_exp2f)
#define EXP2F(x) __builtin_amdgcn_exp2f(x)
#else
#define EXP2F(x) exp2f(x)
#endif
#if __has_builtin(__builtin_amdgcn_rcpf)
#define RCPF(x) __builtin_amdgcn_rcpf(x)
#else
#define RCPF(x) (1.0f / (x))
#endif

// 16B async global->LDS. LDS dest wave-uniform + lane*16; global addr per-lane.
__device__ __forceinline__ void load_lds16(const void* g, void* l) {
  __builtin_amdgcn_global_load_lds(
      (const __attribute__((address_space(1))) uint32_t*)g,
      (__attribute__((address_space(3))) uint32_t*)l, 16, 0, 0);
}

// DPP row_ror add tree: 16-lane reduction entirely on the VALU pipe.
template <int CTRL>
__device__ __forceinline__ float ror_add(float v) {
  int r = __builtin_amdgcn_update_dpp(0, __builtin_bit_cast(int, v), CTRL, 0xf, 0xf, true);
  return v + __builtin_bit_cast(float, r);
}
__device__ __forceinline__ float red16(float v) {
  v = ror_add<0x128>(v);   // ROW_ROR:8
  v = ror_add<0x124>(v);   // ROW_ROR:4
  v = ror_add<0x122>(v);   // ROW_ROR:2
  v = ror_add<0x121>(v);   // ROW_ROR:1
  return v;
}

// ---- prep 1: W f32 -> bf16, [r][n][kt][lane][8 bf16]: B-frag read for
// (n,kt) is a CONTIGUOUS 1KB block (lane*16 + imm). Conflict-free.
__global__ void prep_w(const float* __restrict__ W, uint32_t* __restrict__ ws) {
  uint32_t t = blockIdx.x * 256u + threadIdx.x;   // 65536 threads, one dword each
  uint32_t c  = t >> 2;
  uint32_t j  = t & 3u;
  uint32_t ln = c & 63u;
  uint32_t kt = (c >> 6) & 3u;
  uint32_t n  = (c >> 8) & 7u;
  uint32_t r  = c >> 11;
  uint32_t o  = n * 16u + (ln & 15u);
  uint32_t k  = kt * 32u + (ln >> 4) * 8u + j * 2u;
  const float2 w2 = *reinterpret_cast<const float2*>(
      W + ((size_t)(r * 128u + o)) * 128u + k);
  ws[t] = f2bf(w2.x) | (f2bf(w2.y) << 16);
}

// ---- prep 2: fold DynamicTanh params.
// wsA  [c][r][col] f32 = a*2log2(e)
// wsMC [c][r][col] u32 = bf16(c+d)<<16 | bf16(-2c)
__global__ void prep_acd(const float* __restrict__ A, const float* __restrict__ C,
                         const float* __restrict__ D, float* __restrict__ oA,
                         uint32_t* __restrict__ oMC) {
  uint32_t t = blockIdx.x * 256u + threadIdx.x;   // 32768 threads
  uint32_t col = t & 127u, r = (t >> 7) & 7u, c = t >> 10;
  uint32_t in = (r * 32u + c) * 128u + col;
  float av = A[in], cv = C[in], dv = D[in];
  uint32_t idx = (c * 8u + r) * 128u + col;
  oA[idx]  = av * 2.88539008177793f;
  oMC[idx] = (f2bf(cv + dv) << 16) | f2bf(-2.f * cv);
}

// r11 skeleton, acd moved to VMEM (L1/L2-hot tables) -> LDS = exactly 32KB
// -> 5 blocks/CU (20 waves). LDS port (the measured 68%-busy bottleneck)
// sheds the acd reads; W stays on the proven single-buffer async-split path.
__global__ __launch_bounds__(NTHREADS, 5)
void rot_kernel(const float* __restrict__ src, const float* __restrict__ data,
                const uint8_t* __restrict__ wsw, const float* __restrict__ wsA,
                const uint32_t* __restrict__ wsMC, float* __restrict__ out)
{
  __shared__ __align__(16) unsigned char ldsW[32768];   // single-buffered W_r

  const uint32_t tid  = threadIdx.x;
  const uint32_t lane = tid & 63u;
  const uint32_t wid  = tid >> 6;     // wave 0..3, owns 16 rows
  const uint32_t l15  = lane & 15u;
  const uint32_t lg   = lane >> 4;

  const uint32_t c0   = blockIdx.x & 31u;
  const uint32_t rowb = (blockIdx.x >> 5) * BM + wid * 16u;

  // ---- stage W_0 (32KB) ----
  #pragma unroll
  for (int j = 0; j < 8; ++j)
    load_lds16(wsw + wid * 1024u + (uint32_t)j * 4096u + lane * 16u,
               &ldsW[wid * 1024u + (uint32_t)j * 4096u]);

  // ---- x (data) in registers, MFMA C/D fragment layout ----
  f32x4 x[8];
  #pragma unroll
  for (int q = 0; q < 4; ++q) {
    const float* xr = data + ((size_t)(rowb + lg * 4 + q) * C_DIM + c0) * D_DIM;
    #pragma unroll
    for (int n = 0; n < 8; ++n) x[n][q] = xr[n * 16 + l15];
  }

  // ---- source A-fragments (bf16, converted once) ----
  bf16x8 af[4];
  {
    const float* sr = src + ((size_t)(rowb + l15) * C_DIM + c0) * D_DIM + lg * 8u;
    #pragma unroll
    for (int kt = 0; kt < 4; ++kt) {
      float4 f0 = *reinterpret_cast<const float4*>(sr + kt * 32);
      float4 f1 = *reinterpret_cast<const float4*>(sr + kt * 32 + 4);
      union { uint32_t u[4]; bf16x8 v; } p;
      p.u[0] = f2bf(f0.x) | (f2bf(f0.y) << 16);
      p.u[1] = f2bf(f0.z) | (f2bf(f0.w) << 16);
      p.u[2] = f2bf(f1.x) | (f2bf(f1.y) << 16);
      p.u[3] = f2bf(f1.z) | (f2bf(f1.w) << 16);
      af[kt] = p.v;
    }
  }

  __syncthreads();   // vmcnt(0) drain: W_0 in LDS

  for (int r = 0; r < R_DIM; ++r) {
    // ---- MFMA phase: V = S @ W_r^T (conflict-free contiguous bq reads) ----
    const uint32_t rb = lane * 16u;
    f32x4 acc[8];
    #pragma unroll
    for (int n = 0; n < 8; ++n) acc[n] = (f32x4){0.f, 0.f, 0.f, 0.f};
    #pragma unroll
    for (int kt = 0; kt < 4; ++kt) {
      #pragma unroll
      for (int nh = 0; nh < 8; nh += 4) {
        bf16x8 bq[4];
        #pragma unroll
        for (int i = 0; i < 4; ++i)
          bq[i] = *reinterpret_cast<const bf16x8*>(
              &ldsW[rb + (uint32_t)(((nh + i) * 4 + kt) * 1024)]);
        #pragma unroll
        for (int i = 0; i < 4; ++i)
          acc[nh + i] = __builtin_amdgcn_mfma_f32_16x16x32_bf16(af[kt], bq[i], acc[nh + i], 0, 0, 0);
      }
    }

    __syncthreads();   // all waves done READING W_r -> safe to overwrite

    const float*    pA = wsA  + (uint32_t)(c0 * 8 + r) * 128u;
    const uint32_t* pM = wsMC + (uint32_t)(c0 * 8 + r) * 128u;

    // ---- acd group-1 loads FIRST (so their wait doesn't imply the stage
    // drain: vmcnt is issue-ordered) ----
    float a2v[4]; uint32_t mcv[4];
    #pragma unroll
    for (int i = 0; i < 4; ++i) {
      a2v[i] = pA[i * 16 + l15];
      mcv[i] = pM[i * 16 + l15];
    }

    // ---- async-split stage of W_{r+1}: drains under the epilogue ----
    if (r < 7) {
      const uint8_t* g = wsw + (uint32_t)(r + 1) * 32768u;
      #pragma unroll
      for (int j = 0; j < 8; ++j)
        load_lds16(g + wid * 1024u + (uint32_t)j * 4096u + lane * 16u,
                   &ldsW[wid * 1024u + (uint32_t)j * 4096u]);
    }

    // ---- epilogue: t = tanh(a*v)*c + d;  x -= 2*t*(t.x)/max(||t||,eps)^2 ----
    f32x4 s2 = {0.f,0.f,0.f,0.f}, tx = {0.f,0.f,0.f,0.f};
    #pragma unroll
    for (int n = 0; n < 4; ++n) {
      float m2c = __builtin_bit_cast(float, mcv[n] << 16);          // bf16->f32
      float cdv = __builtin_bit_cast(float, mcv[n] & 0xffff0000u);
      f32x4 z = acc[n] * a2v[n];
      f32x4 ep;
      #pragma unroll
      for (int q = 0; q < 4; ++q) ep[q] = EXP2F(z[q]);
      ep = ep + 1.0f;
      f32x4 pr;
      #pragma unroll
      for (int q = 0; q < 4; ++q) pr[q] = RCPF(ep[q]);
      f32x4 t = pr * m2c + cdv;
      acc[n] = t;
      s2 = s2 + t * t;
      tx = tx + t * x[n];
    }
    // group-2 acd loads (stage has landed by now; short waits)
    #pragma unroll
    for (int i = 0; i < 4; ++i) {
      a2v[i] = pA[(4 + i) * 16 + l15];
      mcv[i] = pM[(4 + i) * 16 + l15];
    }
    #pragma unroll
    for (int n = 4; n < 8; ++n) {
      float m2c = __builtin_bit_cast(float, mcv[n - 4] << 16);
      float cdv = __builtin_bit_cast(float, mcv[n - 4] & 0xffff0000u);
      f32x4 z = acc[n] * a2v[n - 4];
      f32x4 ep;
      #pragma unroll
      for (int q = 0; q < 4; ++q) ep[q] = EXP2F(z[q]);
      ep = ep + 1.0f;
      f32x4 pr;
      #pragma unroll
      for (int q = 0; q < 4; ++q) pr[q] = RCPF(ep[q]);
      f32x4 t = pr * m2c + cdv;
      acc[n] = t;
      s2 = s2 + t * t;
      tx = tx + t * x[n];
    }
    f32x4 sc;
    #pragma unroll
    for (int q = 0; q < 4; ++q) {
      float s = red16(s2[q]);
      float d = red16(tx[q]);
      sc[q] = -2.f * d * RCPF(fmaxf(s, 1e-24f));
    }
    #pragma unroll
    for (int n = 0; n < 8; ++n)
      x[n] = x[n] + sc * acc[n];

    __syncthreads();   // vmcnt(0): W_{r+1} fully landed before next MFMA phase
  }

  // ---- store ----
  #pragma unroll
  for (int q = 0; q < 4; ++q) {
    float* orow = out + ((size_t)(rowb + lg * 4 + q) * C_DIM + c0) * D_DIM;
    #pragma unroll
    for (int n = 0; n < 8; ++n) orow[n * 16 + l15] = x[n][q];
  }
}

extern "C" void kernel_launch(void* const* d_in, const int* in_sizes, int n_in,
                              void* d_out, int out_size, void* d_ws, size_t ws_size,
                              hipStream_t stream) {
  const float* src  = (const float*)d_in[0];
  const float* data = (const float*)d_in[1];
  const float* W    = (const float*)d_in[2];
  const float* Aa   = (const float*)d_in[3];
  const float* Cc   = (const float*)d_in[4];
  const float* Dd   = (const float*)d_in[5];
  float* out = (float*)d_out;

  uint8_t* wsW  = (uint8_t*)d_ws;              // 256 KB bf16 W, frag-ordered
  uint8_t* wsA  = wsW + 262144;                // 128 KB a2 table (f32)
  uint8_t* wsMC = wsA + 131072;                // 128 KB packed bf16 {cdv|m2c}

  prep_w<<<dim3(256), dim3(256), 0, stream>>>(W, (uint32_t*)wsW);
  prep_acd<<<dim3(128), dim3(256), 0, stream>>>(Aa, Cc, Dd, (float*)wsA, (uint32_t*)wsMC);

  dim3 grid((B_DIM / BM) * C_DIM);   // 2048 workgroups of 256
  dim3 block(NTHREADS);
  rot_kernel<<<grid, block, 0, stream>>>(src, data, wsW, (const float*)wsA,
                                         (const uint32_t*)wsMC, out);
}

// Round 17
// 87.651 us; speedup vs baseline: 1.8158x; 1.8158x over previous
//
#include <hip/hip_runtime.h>
#include <stdint.h>

#define B_DIM 4096
#define C_DIM 32
#define D_DIM 128
#define R_DIM 8
#define BM    64           // 4 waves x 16 rows
#define NTHREADS 256

typedef __bf16 bf16x8 __attribute__((ext_vector_type(8)));
typedef float  f32x4  __attribute__((ext_vector_type(4)));

// f32 -> bf16 bits, round-to-nearest-even
__device__ __forceinline__ uint32_t f2bf(float f) {
  uint32_t u = __float_as_uint(f);
  return (u + 0x7FFFu + ((u >> 16) & 1u)) >> 16;
}

#if __has_builtin(__builtin_amdgcn_exp2f)
#define EXP2F(x) __builtin_amdgcn_exp2f(x)
#else
#define EXP2F(x) exp2f(x)
#endif
#if __has_builtin(__builtin_amdgcn_rcpf)
#define RCPF(x) __builtin_amdgcn_rcpf(x)
#else
#define RCPF(x) (1.0f / (x))
#endif

// 16B async global->LDS. LDS dest wave-uniform + lane*16; global addr per-lane.
__device__ __forceinline__ void load_lds16(const void* g, void* l) {
  __builtin_amdgcn_global_load_lds(
      (const __attribute__((address_space(1))) uint32_t*)g,
      (__attribute__((address_space(3))) uint32_t*)l, 16, 0, 0);
}

// DPP row_ror add tree: 16-lane reduction entirely on the VALU pipe.
template <int CTRL>
__device__ __forceinline__ float ror_add(float v) {
  int r = __builtin_amdgcn_update_dpp(0, __builtin_bit_cast(int, v), CTRL, 0xf, 0xf, true);
  return v + __builtin_bit_cast(float, r);
}
__device__ __forceinline__ float red16(float v) {
  v = ror_add<0x128>(v);   // ROW_ROR:8
  v = ror_add<0x124>(v);   // ROW_ROR:4
  v = ror_add<0x122>(v);   // ROW_ROR:2
  v = ror_add<0x121>(v);   // ROW_ROR:1
  return v;
}

// ---- prep 1: W f32 -> bf16, [r][n][kt][lane][8 bf16]: B-frag read for
// (n,kt) is a CONTIGUOUS 1KB block (lane*16 + imm). Conflict-free.
__global__ void prep_w(const float* __restrict__ W, uint32_t* __restrict__ ws) {
  uint32_t t = blockIdx.x * 256u + threadIdx.x;   // 65536 threads, one dword each
  uint32_t c  = t >> 2;
  uint32_t j  = t & 3u;
  uint32_t ln = c & 63u;
  uint32_t kt = (c >> 6) & 3u;
  uint32_t n  = (c >> 8) & 7u;
  uint32_t r  = c >> 11;
  uint32_t o  = n * 16u + (ln & 15u);
  uint32_t k  = kt * 32u + (ln >> 4) * 8u + j * 2u;
  const float2 w2 = *reinterpret_cast<const float2*>(
      W + ((size_t)(r * 128u + o)) * 128u + k);
  ws[t] = f2bf(w2.x) | (f2bf(w2.y) << 16);
}

// ---- prep 2: fold DynamicTanh params.
// wsA  [c][r][col] f32 = a*2log2(e)
// wsMC [c][r][col] u32 = bf16(c+d)<<16 | bf16(-2c)
__global__ void prep_acd(const float* __restrict__ A, const float* __restrict__ C,
                         const float* __restrict__ D, float* __restrict__ oA,
                         uint32_t* __restrict__ oMC) {
  uint32_t t = blockIdx.x * 256u + threadIdx.x;   // 32768 threads
  uint32_t col = t & 127u, r = (t >> 7) & 7u, c = t >> 10;
  uint32_t in = (r * 32u + c) * 128u + col;
  float av = A[in], cv = C[in], dv = D[in];
  uint32_t idx = (c * 8u + r) * 128u + col;
  oA[idx]  = av * 2.88539008177793f;
  oMC[idx] = (f2bf(cv + dv) << 16) | f2bf(-2.f * cv);
}

// r11 skeleton; acd via VMEM (L1/L2-hot 4KB tables) takes ~17% off the LDS
// port (the most-utilized resource) at UNCHANGED occupancy: 4 waves/SIMD is
// this kernel's honest VGPR budget (r6/r14/r16 all spilled below it).
__global__ __launch_bounds__(NTHREADS, 4)
void rot_kernel(const float* __restrict__ src, const float* __restrict__ data,
                const uint8_t* __restrict__ wsw, const float* __restrict__ wsA,
                const uint32_t* __restrict__ wsMC, float* __restrict__ out)
{
  __shared__ __align__(16) unsigned char ldsW[32768];   // single-buffered W_r

  const uint32_t tid  = threadIdx.x;
  const uint32_t lane = tid & 63u;
  const uint32_t wid  = tid >> 6;     // wave 0..3, owns 16 rows
  const uint32_t l15  = lane & 15u;
  const uint32_t lg   = lane >> 4;

  const uint32_t c0   = blockIdx.x & 31u;
  const uint32_t rowb = (blockIdx.x >> 5) * BM + wid * 16u;

  // ---- stage W_0 (32KB) ----
  #pragma unroll
  for (int j = 0; j < 8; ++j)
    load_lds16(wsw + wid * 1024u + (uint32_t)j * 4096u + lane * 16u,
               &ldsW[wid * 1024u + (uint32_t)j * 4096u]);

  // ---- x (data) in registers, MFMA C/D fragment layout ----
  f32x4 x[8];
  #pragma unroll
  for (int q = 0; q < 4; ++q) {
    const float* xr = data + ((size_t)(rowb + lg * 4 + q) * C_DIM + c0) * D_DIM;
    #pragma unroll
    for (int n = 0; n < 8; ++n) x[n][q] = xr[n * 16 + l15];
  }

  // ---- source A-fragments (bf16, converted once) ----
  bf16x8 af[4];
  {
    const float* sr = src + ((size_t)(rowb + l15) * C_DIM + c0) * D_DIM + lg * 8u;
    #pragma unroll
    for (int kt = 0; kt < 4; ++kt) {
      float4 f0 = *reinterpret_cast<const float4*>(sr + kt * 32);
      float4 f1 = *reinterpret_cast<const float4*>(sr + kt * 32 + 4);
      union { uint32_t u[4]; bf16x8 v; } p;
      p.u[0] = f2bf(f0.x) | (f2bf(f0.y) << 16);
      p.u[1] = f2bf(f0.z) | (f2bf(f0.w) << 16);
      p.u[2] = f2bf(f1.x) | (f2bf(f1.y) << 16);
      p.u[3] = f2bf(f1.z) | (f2bf(f1.w) << 16);
      af[kt] = p.v;
    }
  }

  __syncthreads();   // vmcnt(0) drain: W_0 in LDS

  for (int r = 0; r < R_DIM; ++r) {
    // ---- MFMA phase: V = S @ W_r^T (conflict-free contiguous bq reads) ----
    const uint32_t rb = lane * 16u;
    f32x4 acc[8];
    #pragma unroll
    for (int n = 0; n < 8; ++n) acc[n] = (f32x4){0.f, 0.f, 0.f, 0.f};
    #pragma unroll
    for (int kt = 0; kt < 4; ++kt) {
      #pragma unroll
      for (int nh = 0; nh < 8; nh += 4) {
        bf16x8 bq[4];
        #pragma unroll
        for (int i = 0; i < 4; ++i)
          bq[i] = *reinterpret_cast<const bf16x8*>(
              &ldsW[rb + (uint32_t)(((nh + i) * 4 + kt) * 1024)]);
        #pragma unroll
        for (int i = 0; i < 4; ++i)
          acc[nh + i] = __builtin_amdgcn_mfma_f32_16x16x32_bf16(af[kt], bq[i], acc[nh + i], 0, 0, 0);
      }
    }

    __syncthreads();   // all waves done READING W_r -> safe to overwrite

    // ---- all 16 acd loads issue FIRST (vmcnt is issue-ordered: their waits
    // complete without draining the stage issued below) ----
    const float*    pA = wsA  + (uint32_t)(c0 * 8 + r) * 128u;
    const uint32_t* pM = wsMC + (uint32_t)(c0 * 8 + r) * 128u;
    float a2v[8]; uint32_t mcv[8];
    #pragma unroll
    for (int i = 0; i < 8; ++i) {
      a2v[i] = pA[i * 16 + l15];
      mcv[i] = pM[i * 16 + l15];
    }

    // ---- async-split stage of W_{r+1}: drains under the epilogue ----
    if (r < 7) {
      const uint8_t* g = wsw + (uint32_t)(r + 1) * 32768u;
      #pragma unroll
      for (int j = 0; j < 8; ++j)
        load_lds16(g + wid * 1024u + (uint32_t)j * 4096u + lane * 16u,
                   &ldsW[wid * 1024u + (uint32_t)j * 4096u]);
    }

    // ---- epilogue: t = tanh(a*v)*c + d;  x -= 2*t*(t.x)/max(||t||,eps)^2 ----
    f32x4 s2 = {0.f,0.f,0.f,0.f}, tx = {0.f,0.f,0.f,0.f};
    #pragma unroll
    for (int n = 0; n < 8; ++n) {
      float m2c = __builtin_bit_cast(float, mcv[n] << 16);          // bf16->f32
      float cdv = __builtin_bit_cast(float, mcv[n] & 0xffff0000u);
      f32x4 z = acc[n] * a2v[n];
      f32x4 ep;
      #pragma unroll
      for (int q = 0; q < 4; ++q) ep[q] = EXP2F(z[q]);
      ep = ep + 1.0f;
      f32x4 pr;
      #pragma unroll
      for (int q = 0; q < 4; ++q) pr[q] = RCPF(ep[q]);
      f32x4 t = pr * m2c + cdv;
      acc[n] = t;
      s2 = s2 + t * t;
      tx = tx + t * x[n];
    }
    f32x4 sc;
    #pragma unroll
    for (int q = 0; q < 4; ++q) {
      float s = red16(s2[q]);
      float d = red16(tx[q]);
      sc[q] = -2.f * d * RCPF(fmaxf(s, 1e-24f));
    }
    #pragma unroll
    for (int n = 0; n < 8; ++n)
      x[n] = x[n] + sc * acc[n];

    __syncthreads();   // vmcnt(0): W_{r+1} fully landed before next MFMA phase
  }

  // ---- store ----
  #pragma unroll
  for (int q = 0; q < 4; ++q) {
    float* orow = out + ((size_t)(rowb + lg * 4 + q) * C_DIM + c0) * D_DIM;
    #pragma unroll
    for (int n = 0; n < 8; ++n) orow[n * 16 + l15] = x[n][q];
  }
}

extern "C" void kernel_launch(void* const* d_in, const int* in_sizes, int n_in,
                              void* d_out, int out_size, void* d_ws, size_t ws_size,
                              hipStream_t stream) {
  const float* src  = (const float*)d_in[0];
  const float* data = (const float*)d_in[1];
  const float* W    = (const float*)d_in[2];
  const float* Aa   = (const float*)d_in[3];
  const float* Cc   = (const float*)d_in[4];
  const float* Dd   = (const float*)d_in[5];
  float* out = (float*)d_out;

  uint8_t* wsW  = (uint8_t*)d_ws;              // 256 KB bf16 W, frag-ordered
  uint8_t* wsA  = wsW + 262144;                // 128 KB a2 table (f32)
  uint8_t* wsMC = wsA + 131072;                // 128 KB packed bf16 {cdv|m2c}

  prep_w<<<dim3(256), dim3(256), 0, stream>>>(W, (uint32_t*)wsW);
  prep_acd<<<dim3(128), dim3(256), 0, stream>>>(Aa, Cc, Dd, (float*)wsA, (uint32_t*)wsMC);

  dim3 grid((B_DIM / BM) * C_DIM);   // 2048 workgroups of 256
  dim3 block(NTHREADS);
  rot_kernel<<<grid, block, 0, stream>>>(src, data, wsW, (const float*)wsA,
                                         (const uint32_t*)wsMC, out);
}

// Round 18
// 83.516 us; speedup vs baseline: 1.9057x; 1.0495x over previous
//
#include <hip/hip_runtime.h>
#include <stdint.h>

#define B_DIM 4096
#define C_DIM 32
#define D_DIM 128
#define R_DIM 8
#define BM    64           // 4 waves x 16 rows
#define NTHREADS 256

typedef __bf16 bf16x8 __attribute__((ext_vector_type(8)));
typedef float  f32x4  __attribute__((ext_vector_type(4)));

// f32 -> bf16 bits, round-to-nearest-even
__device__ __forceinline__ uint32_t f2bf(float f) {
  uint32_t u = __float_as_uint(f);
  return (u + 0x7FFFu + ((u >> 16) & 1u)) >> 16;
}

#if __has_builtin(__builtin_amdgcn_exp2f)
#define EXP2F(x) __builtin_amdgcn_exp2f(x)
#else
#define EXP2F(x) exp2f(x)
#endif
#if __has_builtin(__builtin_amdgcn_rcpf)
#define RCPF(x) __builtin_amdgcn_rcpf(x)
#else
#define RCPF(x) (1.0f / (x))
#endif

// 16B async global->LDS. LDS dest wave-uniform + lane*16; global addr per-lane.
__device__ __forceinline__ void load_lds16(const void* g, void* l) {
  __builtin_amdgcn_global_load_lds(
      (const __attribute__((address_space(1))) uint32_t*)g,
      (__attribute__((address_space(3))) uint32_t*)l, 16, 0, 0);
}

// DPP row_ror add tree: 16-lane reduction entirely on the VALU pipe.
template <int CTRL>
__device__ __forceinline__ float ror_add(float v) {
  int r = __builtin_amdgcn_update_dpp(0, __builtin_bit_cast(int, v), CTRL, 0xf, 0xf, true);
  return v + __builtin_bit_cast(float, r);
}
__device__ __forceinline__ float red16(float v) {
  v = ror_add<0x128>(v);   // ROW_ROR:8
  v = ror_add<0x124>(v);   // ROW_ROR:4
  v = ror_add<0x122>(v);   // ROW_ROR:2
  v = ror_add<0x121>(v);   // ROW_ROR:1
  return v;
}

// ---- prep 1: W f32 -> bf16, [r][n][kt][lane][8 bf16]: B-frag read for
// (n,kt) is a CONTIGUOUS 1KB block (lane*16 + imm). Conflict-free.
__global__ void prep_w(const float* __restrict__ W, uint32_t* __restrict__ ws) {
  uint32_t t = blockIdx.x * 256u + threadIdx.x;   // 65536 threads, one dword each
  uint32_t c  = t >> 2;
  uint32_t j  = t & 3u;
  uint32_t ln = c & 63u;
  uint32_t kt = (c >> 6) & 3u;
  uint32_t n  = (c >> 8) & 7u;
  uint32_t r  = c >> 11;
  uint32_t o  = n * 16u + (ln & 15u);
  uint32_t k  = kt * 32u + (ln >> 4) * 8u + j * 2u;
  const float2 w2 = *reinterpret_cast<const float2*>(
      W + ((size_t)(r * 128u + o)) * 128u + k);
  ws[t] = f2bf(w2.x) | (f2bf(w2.y) << 16);
}

// ---- prep 2: fold DynamicTanh params.
// wsA  [c][r][col] f32 = a*2log2(e)
// wsMC [c][r][col] u32 = bf16(c+d)<<16 | bf16(-2c)
__global__ void prep_acd(const float* __restrict__ A, const float* __restrict__ C,
                         const float* __restrict__ D, float* __restrict__ oA,
                         uint32_t* __restrict__ oMC) {
  uint32_t t = blockIdx.x * 256u + threadIdx.x;   // 32768 threads
  uint32_t col = t & 127u, r = (t >> 7) & 7u, c = t >> 10;
  uint32_t in = (r * 32u + c) * 128u + col;
  float av = A[in], cv = C[in], dv = D[in];
  uint32_t idx = (c * 8u + r) * 128u + col;
  oA[idx]  = av * 2.88539008177793f;
  oMC[idx] = (f2bf(cv + dv) << 16) | f2bf(-2.f * cv);
}

__global__ __launch_bounds__(NTHREADS, 4)
void rot_kernel(const float* __restrict__ src, const float* __restrict__ data,
                const uint8_t* __restrict__ wsw, const uint8_t* __restrict__ wsA,
                const uint8_t* __restrict__ wsMC, float* __restrict__ out)
{
  __shared__ __align__(16) unsigned char ldsW[32768];   // single-buffered W_r
  __shared__ __align__(16) float    ldsA[8 * 128];      // 4 KB a2 (f32)
  __shared__ __align__(16) uint32_t ldsMC[8 * 128];     // 4 KB packed bf16 {cdv|m2c}

  const uint32_t tid  = threadIdx.x;
  const uint32_t lane = tid & 63u;
  const uint32_t wid  = tid >> 6;     // wave 0..3, owns 16 rows
  const uint32_t l15  = lane & 15u;
  const uint32_t lg   = lane >> 4;

  const uint32_t c0   = blockIdx.x & 31u;
  const uint32_t rowb = (blockIdx.x >> 5) * BM + wid * 16u;

  // ---- stage W_0 (32KB) + acd tables (8KB) for this c0 ----
  #pragma unroll
  for (int j = 0; j < 8; ++j)
    load_lds16(wsw + wid * 1024u + (uint32_t)j * 4096u + lane * 16u,
               &ldsW[wid * 1024u + (uint32_t)j * 4096u]);
  load_lds16(wsA + (uint32_t)c0 * 4096u + wid * 1024u + lane * 16u,
             (uint8_t*)ldsA + wid * 1024u);
  load_lds16(wsMC + (uint32_t)c0 * 4096u + wid * 1024u + lane * 16u,
             (uint8_t*)ldsMC + wid * 1024u);

  // ---- x (data) in registers, MFMA C/D fragment layout ----
  f32x4 x[8];
  #pragma unroll
  for (int q = 0; q < 4; ++q) {
    const float* xr = data + ((size_t)(rowb + lg * 4 + q) * C_DIM + c0) * D_DIM;
    #pragma unroll
    for (int n = 0; n < 8; ++n) x[n][q] = xr[n * 16 + l15];
  }

  // ---- source A-fragments (bf16, converted once) ----
  bf16x8 af[4];
  {
    const float* sr = src + ((size_t)(rowb + l15) * C_DIM + c0) * D_DIM + lg * 8u;
    #pragma unroll
    for (int kt = 0; kt < 4; ++kt) {
      float4 f0 = *reinterpret_cast<const float4*>(sr + kt * 32);
      float4 f1 = *reinterpret_cast<const float4*>(sr + kt * 32 + 4);
      union { uint32_t u[4]; bf16x8 v; } p;
      p.u[0] = f2bf(f0.x) | (f2bf(f0.y) << 16);
      p.u[1] = f2bf(f0.z) | (f2bf(f0.w) << 16);
      p.u[2] = f2bf(f1.x) | (f2bf(f1.y) << 16);
      p.u[3] = f2bf(f1.z) | (f2bf(f1.w) << 16);
      af[kt] = p.v;
    }
  }

  // ---- anti-convoy stagger (AFTER prologue loads so HBM latency hides
  // under the sleep). Co-resident set is ~{bid, bid+256, bid+512, bid+768};
  // offsets of ~0/2.5k/5k/7.5k cy (~1/4 of the ~10-13k cy r-period) put the
  // 4 blocks in different phases so the LDS-port-bound MFMA phase of one
  // overlaps the VALU/trans epilogue of the others. (r13's 512-1536cy
  // offsets were 10x too small to separate phases.)
  {
    uint32_t g = (blockIdx.x >> 8) & 3u;
    if (g == 1) __builtin_amdgcn_s_sleep(40);    // ~2560 cy
    if (g == 2) __builtin_amdgcn_s_sleep(80);    // ~5120 cy
    if (g == 3) __builtin_amdgcn_s_sleep(120);   // ~7680 cy
  }

  __syncthreads();   // vmcnt(0) drain: W_0 + acd in LDS

  for (int r = 0; r < R_DIM; ++r) {
    // ---- MFMA phase: V = S @ W_r^T (conflict-free contiguous bq reads) ----
    const uint32_t rb = lane * 16u;
    f32x4 acc[8];
    #pragma unroll
    for (int n = 0; n < 8; ++n) acc[n] = (f32x4){0.f, 0.f, 0.f, 0.f};
    #pragma unroll
    for (int kt = 0; kt < 4; ++kt) {
      #pragma unroll
      for (int nh = 0; nh < 8; nh += 4) {
        bf16x8 bq[4];
        #pragma unroll
        for (int i = 0; i < 4; ++i)
          bq[i] = *reinterpret_cast<const bf16x8*>(
              &ldsW[rb + (uint32_t)(((nh + i) * 4 + kt) * 1024)]);
        #pragma unroll
        for (int i = 0; i < 4; ++i)
          acc[nh + i] = __builtin_amdgcn_mfma_f32_16x16x32_bf16(af[kt], bq[i], acc[nh + i], 0, 0, 0);
      }
    }

    __syncthreads();   // all waves done READING W_r -> safe to overwrite

    // ---- async-split stage of W_{r+1}: issue now, drains under epilogue ----
    if (r < 7) {
      const uint8_t* g = wsw + (uint32_t)(r + 1) * 32768u;
      #pragma unroll
      for (int j = 0; j < 8; ++j)
        load_lds16(g + wid * 1024u + (uint32_t)j * 4096u + lane * 16u,
                   &ldsW[wid * 1024u + (uint32_t)j * 4096u]);
    }

    // ---- epilogue: t = tanh(a*v)*c + d;  x -= 2*t*(t.x)/max(||t||,eps)^2 ----
    f32x4 s2 = {0.f,0.f,0.f,0.f}, tx = {0.f,0.f,0.f,0.f};
    #pragma unroll
    for (int n = 0; n < 8; ++n) {
      float    a2  = ldsA [r * 128 + n * 16 + l15];   // broadcast, conflict-free
      uint32_t mcu = ldsMC[r * 128 + n * 16 + l15];
      float m2c = __builtin_bit_cast(float, mcu << 16);          // bf16 -> f32
      float cdv = __builtin_bit_cast(float, mcu & 0xffff0000u);  // bf16 -> f32
      f32x4 z = acc[n] * a2;
      f32x4 ep;
      #pragma unroll
      for (int q = 0; q < 4; ++q) ep[q] = EXP2F(z[q]);
      ep = ep + 1.0f;
      f32x4 pr;
      #pragma unroll
      for (int q = 0; q < 4; ++q) pr[q] = RCPF(ep[q]);
      f32x4 t = pr * m2c + cdv;
      acc[n] = t;
      s2 = s2 + t * t;
      tx = tx + t * x[n];
    }
    f32x4 sc;
    #pragma unroll
    for (int q = 0; q < 4; ++q) {
      float s = red16(s2[q]);
      float d = red16(tx[q]);
      sc[q] = -2.f * d * RCPF(fmaxf(s, 1e-24f));
    }
    #pragma unroll
    for (int n = 0; n < 8; ++n)
      x[n] = x[n] + sc * acc[n];

    __syncthreads();   // vmcnt(0): W_{r+1} fully landed before next MFMA phase
  }

  // ---- store ----
  #pragma unroll
  for (int q = 0; q < 4; ++q) {
    float* orow = out + ((size_t)(rowb + lg * 4 + q) * C_DIM + c0) * D_DIM;
    #pragma unroll
    for (int n = 0; n < 8; ++n) orow[n * 16 + l15] = x[n][q];
  }
}

extern "C" void kernel_launch(void* const* d_in, const int* in_sizes, int n_in,
                              void* d_out, int out_size, void* d_ws, size_t ws_size,
                              hipStream_t stream) {
  const float* src  = (const float*)d_in[0];
  const float* data = (const float*)d_in[1];
  const float* W    = (const float*)d_in[2];
  const float* Aa   = (const float*)d_in[3];
  const float* Cc   = (const float*)d_in[4];
  const float* Dd   = (const float*)d_in[5];
  float* out = (float*)d_out;

  uint8_t* wsW  = (uint8_t*)d_ws;              // 256 KB bf16 W, frag-ordered
  uint8_t* wsA  = wsW + 262144;                // 128 KB a2 table (f32)
  uint8_t* wsMC = wsA + 131072;                // 128 KB packed bf16 {cdv|m2c}

  prep_w<<<dim3(256), dim3(256), 0, stream>>>(W, (uint32_t*)wsW);
  prep_acd<<<dim3(128), dim3(256), 0, stream>>>(Aa, Cc, Dd, (float*)wsA, (uint32_t*)wsMC);

  dim3 grid((B_DIM / BM) * C_DIM);   // 2048 workgroups of 256
  dim3 block(NTHREADS);
  rot_kernel<<<grid, block, 0, stream>>>(src, data, wsW, wsA, wsMC, out);
}